// Round 4
// baseline (445.040 us; speedup 1.0000x reference)
//
#include <hip/hip_runtime.h>
#include <hip/hip_bf16.h>

#define HIDDEN 896
#define HEADS 7
#define HDIM 128
#define BB 4
#define TT 2048
#define MTOT (BB*TT)   // 8192

typedef short bf16x8 __attribute__((ext_vector_type(8)));
typedef float f32x4 __attribute__((ext_vector_type(4)));

__device__ __forceinline__ short f2bf(float f) {
    union { float f; unsigned u; } v; v.f = f;
    unsigned r = (v.u + 0x7FFF + ((v.u >> 16) & 1)) >> 16;
    return (short)r;
}

// ---------------- kernel 1: cast x (fp32) -> bf16 ----------------
__global__ __launch_bounds__(256) void cast_x_kernel(const float* __restrict__ x,
                                                     short* __restrict__ xb) {
    int base = (blockIdx.x * 256 + threadIdx.x) * 4;
    if (base < MTOT * HIDDEN) {
        float4 v = *(const float4*)(x + base);
        short4 o;
        o.x = f2bf(v.x); o.y = f2bf(v.y); o.z = f2bf(v.z); o.w = f2bf(v.w);
        *(short4*)(xb + base) = o;
    }
}

// cast Wo fp32[896][896] -> bf16 (already B^T form [n][k])
__global__ __launch_bounds__(256) void cast_wo_kernel(const float* __restrict__ src,
                                                      short* __restrict__ dst) {
    int base = (blockIdx.x * 256 + threadIdx.x) * 4;
    if (base < HIDDEN * HIDDEN) {
        float4 v = *(const float4*)(src + base);
        short4 o;
        o.x = f2bf(v.x); o.y = f2bf(v.y); o.z = f2bf(v.z); o.w = f2bf(v.w);
        *(short4*)(dst + base) = o;
    }
}

// transpose-cast Wq/Wk/Wv fp32 [head][896 k][128 n] -> bf16 Wt[type*7+head][128 n][896 k]
__global__ __launch_bounds__(256) void transpose_cast_w(
    const float* __restrict__ Wq, const float* __restrict__ Wk,
    const float* __restrict__ Wv, short* __restrict__ Wt)
{
    __shared__ float tile[32][33];
    const int z = blockIdx.z;
    const int type = z / 7, head = z % 7;
    const float* src = (type == 0 ? Wq : (type == 1 ? Wk : Wv)) + head * (HIDDEN * HDIM);
    short* dst = Wt + (size_t)z * (HDIM * HIDDEN);
    const int r0 = blockIdx.x * 32, c0 = blockIdx.y * 32;
    const int tx = threadIdx.x & 31, ty = threadIdx.x >> 5;  // 32 x 8
    for (int i = 0; i < 4; i++)
        tile[ty * 4 + i][tx] = src[(r0 + ty * 4 + i) * HDIM + c0 + tx];
    __syncthreads();
    for (int i = 0; i < 4; i++)
        dst[(c0 + ty * 4 + i) * HIDDEN + r0 + tx] = f2bf(tile[tx][ty * 4 + i]);
}

// ---------------- kernel 2: QKV projection GEMM (128x128 tile) ----------------
__global__ __launch_bounds__(256) void qkv_gemm(
    const short* __restrict__ xb, const short* __restrict__ Wt,
    short* __restrict__ Q, short* __restrict__ Kk, short* __restrict__ Vt)
{
    __shared__ short Ash[128 * 40];
    __shared__ short Bsh[128 * 40];
    const int m0 = blockIdx.x * 128;
    const int z = blockIdx.y;
    const int head = z % 7, type = z / 7;
    const short* Wz = Wt + (size_t)z * (HDIM * HIDDEN);

    const int tid = threadIdx.x;
    const int wave = tid >> 6, lane = tid & 63;
    const int quad = lane >> 4, l16 = lane & 15;
    const int wm = (wave >> 1) * 64, wn = (wave & 1) * 64;

    f32x4 acc[4][4] = {};
    const int sr = tid >> 2, sc = (tid & 3) * 8;

    for (int k0 = 0; k0 < HIDDEN; k0 += 32) {
        bf16x8 a0 = *(const bf16x8*)(xb + (size_t)(m0 + sr) * HIDDEN + k0 + sc);
        bf16x8 a1 = *(const bf16x8*)(xb + (size_t)(m0 + sr + 64) * HIDDEN + k0 + sc);
        bf16x8 b0 = *(const bf16x8*)(Wz + (size_t)sr * HIDDEN + k0 + sc);
        bf16x8 b1 = *(const bf16x8*)(Wz + (size_t)(sr + 64) * HIDDEN + k0 + sc);
        __syncthreads();
        *(bf16x8*)(Ash + sr * 40 + sc) = a0;
        *(bf16x8*)(Ash + (sr + 64) * 40 + sc) = a1;
        *(bf16x8*)(Bsh + sr * 40 + sc) = b0;
        *(bf16x8*)(Bsh + (sr + 64) * 40 + sc) = b1;
        __syncthreads();
        bf16x8 af[4], bfr[4];
        for (int mi = 0; mi < 4; mi++)
            af[mi] = *(const bf16x8*)(Ash + (wm + mi * 16 + l16) * 40 + quad * 8);
        for (int ni = 0; ni < 4; ni++)
            bfr[ni] = *(const bf16x8*)(Bsh + (wn + ni * 16 + l16) * 40 + quad * 8);
        for (int mi = 0; mi < 4; mi++)
            for (int ni = 0; ni < 4; ni++)
                acc[mi][ni] = __builtin_amdgcn_mfma_f32_16x16x32_bf16(af[mi], bfr[ni], acc[mi][ni], 0, 0, 0);
    }

    const size_t base = (size_t)head * (MTOT * HDIM);
    if (type == 0) {
        // fold softmax scale AND log2(e) into Q (softmax done in exp2 domain)
        const float qs = 0.08838834764831845f * 1.4426950408889634f;
        for (int mi = 0; mi < 4; mi++)
            for (int ni = 0; ni < 4; ni++)
                for (int r = 0; r < 4; r++) {
                    int m = m0 + wm + mi * 16 + quad * 4 + r;
                    int n = wn + ni * 16 + l16;
                    Q[base + (size_t)m * HDIM + n] = f2bf(acc[mi][ni][r] * qs);
                }
    } else if (type == 1) {
        for (int mi = 0; mi < 4; mi++)
            for (int ni = 0; ni < 4; ni++)
                for (int r = 0; r < 4; r++) {
                    int m = m0 + wm + mi * 16 + quad * 4 + r;
                    int n = wn + ni * 16 + l16;
                    Kk[base + (size_t)m * HDIM + n] = f2bf(acc[mi][ni][r]);
                }
    } else {
        for (int mi = 0; mi < 4; mi++)
            for (int ni = 0; ni < 4; ni++) {
                int m = m0 + wm + mi * 16 + quad * 4;
                int bb = m >> 11, t = m & 2047;
                int n = wn + ni * 16 + l16;
                short4 o;
                o.x = f2bf(acc[mi][ni][0]); o.y = f2bf(acc[mi][ni][1]);
                o.z = f2bf(acc[mi][ni][2]); o.w = f2bf(acc[mi][ni][3]);
                *(short4*)(Vt + base + (size_t)bb * (HDIM * TT) + (size_t)n * TT + t) = o;
            }
    }
}

// ---------------- kernel 3: fano flash attention v4 ----------------
// 64-row q-tile per block (wave owns 16 rows), LDS-staged K/V, register prefetch.
// grid: (T/64=32, B=4, HEADS=7), block 256. LDS 45 KB -> 3 blocks/CU.
__global__ __launch_bounds__(256, 3) void fano_attn(
    const short* __restrict__ Q, const short* __restrict__ K, const short* __restrict__ Vt,
    short* __restrict__ Ocat, const int* __restrict__ iscp)
{
    __shared__ short Ks[64 * 136];
    __shared__ short Vs[128 * 72];
    __shared__ short Ps[4][16 * 72];

    const int causal = *iscp;
    const int qt = causal ? ((int)gridDim.x - 1 - blockIdx.x) : blockIdx.x;
    const int q0 = qt * 64;
    const int b = blockIdx.y, h = blockIdx.z;
    const int tid = threadIdx.x, wave = tid >> 6, lane = tid & 63;
    const int quad = lane >> 4, l16 = lane & 15;
    const int iw = q0 + wave * 16;   // wave's min q-row

    const short* Qb = Q + (size_t)(h * MTOT + b * TT + q0) * HDIM;
    const short* Kb = K + (size_t)(h * MTOT + b * TT) * HDIM;
    const short* Vb = Vt + (size_t)h * MTOT * HDIM + (size_t)b * HDIM * TT;

    // Q fragments direct from global (one-time; scale*log2e folded at projection)
    bf16x8 qf[4];
    for (int ks = 0; ks < 4; ks++)
        qf[ks] = *(const bf16x8*)(Qb + (size_t)(wave * 16 + l16) * HDIM + ks * 32 + quad * 8);

    float mrun[4], lrun[4];
    f32x4 oacc[8] = {};
    int irow[4];
    for (int r = 0; r < 4; r++) {
        mrun[r] = -1e30f; lrun[r] = 0.f;
        irow[r] = iw + quad * 4 + r;
    }

    // staging maps (16B chunks, 4 per thread per tile)
    int krow[4], kcol[4], vrow[4], vcol[4];
    for (int i = 0; i < 4; i++) {
        int c = tid + i * 256;
        krow[i] = c >> 4; kcol[i] = (c & 15) * 8;
        vrow[i] = c >> 3; vcol[i] = (c & 7) * 8;
    }

    const int send = causal ? (q0 + 64) : TT;

    bf16x8 kreg[4], vreg[4];
    for (int i = 0; i < 4; i++) {
        kreg[i] = *(const bf16x8*)(Kb + (size_t)krow[i] * HDIM + kcol[i]);
        vreg[i] = *(const bf16x8*)(Vb + (size_t)vrow[i] * TT + vcol[i]);
    }

    int d7b = (l16 - h + 7) % 7;   // (s - h) mod 7 at s = s0 + l16
    short* Pw = &Ps[wave][0];

    for (int s0 = 0; s0 < send; s0 += 64) {
        __syncthreads();
        for (int i = 0; i < 4; i++) {
            *(bf16x8*)(Ks + krow[i] * 136 + kcol[i]) = kreg[i];
            *(bf16x8*)(Vs + vrow[i] * 72 + vcol[i]) = vreg[i];
        }
        __syncthreads();

        int sn = s0 + 64; if (sn >= send) sn = s0;
        const short* Kn = Kb + (size_t)sn * HDIM;
        const short* Vn = Vb + sn;
        for (int i = 0; i < 4; i++) {
            kreg[i] = *(const bf16x8*)(Kn + (size_t)krow[i] * HDIM + kcol[i]);
            vreg[i] = *(const bf16x8*)(Vn + (size_t)vrow[i] * TT + vcol[i]);
        }

        // S = Q K^T  (log2 domain)
        f32x4 sacc[4] = {};
        for (int ni = 0; ni < 4; ni++)
            for (int ks = 0; ks < 4; ks++) {
                bf16x8 bk = *(const bf16x8*)(Ks + (ni * 16 + l16) * 136 + ks * 32 + quad * 8);
                sacc[ni] = __builtin_amdgcn_mfma_f32_16x16x32_bf16(qf[ks], bk, sacc[ni], 0, 0, 0);
            }

        // mask + row max; fast path when only the fano-line term matters
        float mx[4] = {-1e30f, -1e30f, -1e30f, -1e30f};
        const bool full = causal ? (s0 + 80 > iw) : (s0 + 80 > iw && s0 < iw + 32);
        if (full) {
            for (int ni = 0; ni < 4; ni++) {
                int d7 = d7b + 2 * ni; if (d7 >= 7) d7 -= 7;
                bool line = (0x0B >> d7) & 1;
                int s = s0 + ni * 16 + l16;
                for (int r = 0; r < 4; r++) {
                    int i = irow[r];
                    bool ok = causal ? ((s <= i) & (line | (s >= i - 16)))
                                     : (line | ((s >= i - 16) & (s <= i + 16)));
                    float v = ok ? sacc[ni][r] : -1e30f;
                    sacc[ni][r] = v;
                    mx[r] = fmaxf(mx[r], v);
                }
            }
        } else {
            for (int ni = 0; ni < 4; ni++) {
                int d7 = d7b + 2 * ni; if (d7 >= 7) d7 -= 7;
                bool line = (0x0B >> d7) & 1;
                for (int r = 0; r < 4; r++) {
                    float v = line ? sacc[ni][r] : -1e30f;
                    sacc[ni][r] = v;
                    mx[r] = fmaxf(mx[r], v);
                }
            }
        }
        d7b++; if (d7b == 7) d7b = 0;

        for (int off = 1; off < 16; off <<= 1)
            for (int r = 0; r < 4; r++) mx[r] = fmaxf(mx[r], __shfl_xor(mx[r], off));

        float alpha[4], rs[4];
        for (int r = 0; r < 4; r++) {
            float nm = fmaxf(mrun[r], mx[r]);
            alpha[r] = exp2f(mrun[r] - nm);
            mrun[r] = nm;
            rs[r] = 0.f;
        }
        for (int ni = 0; ni < 4; ni++)
            for (int r = 0; r < 4; r++) {
                float p = exp2f(sacc[ni][r] - mrun[r]);
                sacc[ni][r] = p;
                rs[r] += p;
            }
        for (int off = 1; off < 16; off <<= 1)
            for (int r = 0; r < 4; r++) rs[r] += __shfl_xor(rs[r], off);
        for (int r = 0; r < 4; r++) lrun[r] = lrun[r] * alpha[r] + rs[r];
        for (int nj = 0; nj < 8; nj++)
            for (int r = 0; r < 4; r++) oacc[nj][r] *= alpha[r];

        // P: C-layout regs -> wave-private LDS -> A-layout frags
        for (int ni = 0; ni < 4; ni++)
            for (int r = 0; r < 4; r++)
                Pw[(quad * 4 + r) * 72 + ni * 16 + l16] = f2bf(sacc[ni][r]);

        // O += P V
        for (int ks2 = 0; ks2 < 2; ks2++) {
            bf16x8 ap = *(const bf16x8*)(Pw + l16 * 72 + ks2 * 32 + quad * 8);
            for (int nj = 0; nj < 8; nj++) {
                bf16x8 bv = *(const bf16x8*)(Vs + (nj * 16 + l16) * 72 + ks2 * 32 + quad * 8);
                oacc[nj] = __builtin_amdgcn_mfma_f32_16x16x32_bf16(ap, bv, oacc[nj], 0, 0, 0);
            }
        }
    }

    float inv[4];
    for (int r = 0; r < 4; r++) inv[r] = 1.0f / lrun[r];
    short* Obase = Ocat + (size_t)(b * TT) * HIDDEN + h * HDIM;
    for (int nj = 0; nj < 8; nj++)
        for (int r = 0; r < 4; r++)
            Obase[(size_t)irow[r] * HIDDEN + nj * 16 + l16] = f2bf(oacc[nj][r] * inv[r]);
}

// ---------------- kernel 4: output projection (128x128 tile) ----------------
__global__ __launch_bounds__(256) void out_gemm(
    const short* __restrict__ A, const short* __restrict__ Bt, float* __restrict__ out)
{
    __shared__ short Ash[128 * 40];
    __shared__ short Bsh[128 * 40];
    const int m0 = blockIdx.x * 128;
    const int n0 = blockIdx.y * 128;

    const int tid = threadIdx.x;
    const int wave = tid >> 6, lane = tid & 63;
    const int quad = lane >> 4, l16 = lane & 15;
    const int wm = (wave >> 1) * 64, wn = (wave & 1) * 64;

    f32x4 acc[4][4] = {};
    const int sr = tid >> 2, sc = (tid & 3) * 8;

    for (int k0 = 0; k0 < HIDDEN; k0 += 32) {
        bf16x8 a0 = *(const bf16x8*)(A + (size_t)(m0 + sr) * HIDDEN + k0 + sc);
        bf16x8 a1 = *(const bf16x8*)(A + (size_t)(m0 + sr + 64) * HIDDEN + k0 + sc);
        bf16x8 b0 = *(const bf16x8*)(Bt + (size_t)(n0 + sr) * HIDDEN + k0 + sc);
        bf16x8 b1 = *(const bf16x8*)(Bt + (size_t)(n0 + sr + 64) * HIDDEN + k0 + sc);
        __syncthreads();
        *(bf16x8*)(Ash + sr * 40 + sc) = a0;
        *(bf16x8*)(Ash + (sr + 64) * 40 + sc) = a1;
        *(bf16x8*)(Bsh + sr * 40 + sc) = b0;
        *(bf16x8*)(Bsh + (sr + 64) * 40 + sc) = b1;
        __syncthreads();
        bf16x8 af[4], bfr[4];
        for (int mi = 0; mi < 4; mi++)
            af[mi] = *(const bf16x8*)(Ash + (wm + mi * 16 + l16) * 40 + quad * 8);
        for (int ni = 0; ni < 4; ni++)
            bfr[ni] = *(const bf16x8*)(Bsh + (wn + ni * 16 + l16) * 40 + quad * 8);
        for (int mi = 0; mi < 4; mi++)
            for (int ni = 0; ni < 4; ni++)
                acc[mi][ni] = __builtin_amdgcn_mfma_f32_16x16x32_bf16(af[mi], bfr[ni], acc[mi][ni], 0, 0, 0);
    }

    for (int mi = 0; mi < 4; mi++)
        for (int ni = 0; ni < 4; ni++)
            for (int r = 0; r < 4; r++) {
                int m = m0 + wm + mi * 16 + quad * 4 + r;
                int n = n0 + wn + ni * 16 + l16;
                out[(size_t)m * HIDDEN + n] = acc[mi][ni][r];
            }
}

extern "C" void kernel_launch(void* const* d_in, const int* in_sizes, int n_in,
                              void* d_out, int out_size, void* d_ws, size_t ws_size,
                              hipStream_t stream) {
    (void)in_sizes; (void)n_in; (void)out_size; (void)ws_size;
    const float* x  = (const float*)d_in[0];
    const float* Wq = (const float*)d_in[1];
    const float* Wk = (const float*)d_in[2];
    const float* Wv = (const float*)d_in[3];
    const float* Wo = (const float*)d_in[4];
    const int* iscp = (const int*)d_in[5];
    float* out = (float*)d_out;

    short* xb   = (short*)d_ws;                       // 8192*896
    short* Qb   = xb   + (size_t)MTOT * HIDDEN;       // 7*8192*128
    short* Kb   = Qb   + (size_t)HEADS * MTOT * HDIM;
    short* Vtb  = Kb   + (size_t)HEADS * MTOT * HDIM;
    short* Ocat = Vtb  + (size_t)HEADS * MTOT * HDIM; // 8192*896  (aliased with Wt)
    short* Wt   = Ocat;                               // 21*128*896 bf16, used only before attn
    short* Wob  = Ocat + (size_t)MTOT * HIDDEN;       // 896*896

    cast_x_kernel<<<(MTOT * HIDDEN) / (256 * 4), 256, 0, stream>>>(x, xb);
    cast_wo_kernel<<<(HIDDEN * HIDDEN) / (256 * 4), 256, 0, stream>>>(Wo, Wob);
    transpose_cast_w<<<dim3(HIDDEN / 32, HDIM / 32, 21), 256, 0, stream>>>(Wq, Wk, Wv, Wt);
    qkv_gemm<<<dim3(MTOT / 128, 21), 256, 0, stream>>>(xb, Wt, Qb, Kb, Vtb);
    fano_attn<<<dim3(TT / 64, BB, HEADS), 256, 0, stream>>>(Qb, Kb, Vtb, Ocat, iscp);
    out_gemm<<<dim3(MTOT / 128, HIDDEN / 128), 256, 0, stream>>>(Ocat, Wob, out);
}

// Round 5
// 444.554 us; speedup vs baseline: 1.0011x; 1.0011x over previous
//
#include <hip/hip_runtime.h>
#include <hip/hip_bf16.h>

#define HIDDEN 896
#define HEADS 7
#define HDIM 128
#define BB 4
#define TT 2048
#define MTOT (BB*TT)   // 8192
#define CPAD 896       // padded compacted-column count (max 879)

typedef short bf16x8 __attribute__((ext_vector_type(8)));
typedef float f32x4 __attribute__((ext_vector_type(4)));

__device__ __forceinline__ short f2bf(float f) {
    union { float f; unsigned u; } v; v.f = f;
    unsigned r = (v.u + 0x7FFF + ((v.u >> 16) & 1)) >> 16;
    return (short)r;
}

// ---------------- kernel 1: cast x (fp32) -> bf16 ----------------
__global__ __launch_bounds__(256) void cast_x_kernel(const float* __restrict__ x,
                                                     short* __restrict__ xb) {
    int base = (blockIdx.x * 256 + threadIdx.x) * 4;
    if (base < MTOT * HIDDEN) {
        float4 v = *(const float4*)(x + base);
        short4 o;
        o.x = f2bf(v.x); o.y = f2bf(v.y); o.z = f2bf(v.z); o.w = f2bf(v.w);
        *(short4*)(xb + base) = o;
    }
}

// cast Wo fp32[896][896] -> bf16 (already B^T form [n][k])
__global__ __launch_bounds__(256) void cast_wo_kernel(const float* __restrict__ src,
                                                      short* __restrict__ dst) {
    int base = (blockIdx.x * 256 + threadIdx.x) * 4;
    if (base < HIDDEN * HIDDEN) {
        float4 v = *(const float4*)(src + base);
        short4 o;
        o.x = f2bf(v.x); o.y = f2bf(v.y); o.z = f2bf(v.z); o.w = f2bf(v.w);
        *(short4*)(dst + base) = o;
    }
}

// transpose-cast Wq/Wk/Wv fp32 [head][896 k][128 n] -> bf16 Wt[type*7+head][128 n][896 k]
__global__ __launch_bounds__(256) void transpose_cast_w(
    const float* __restrict__ Wq, const float* __restrict__ Wk,
    const float* __restrict__ Wv, short* __restrict__ Wt)
{
    __shared__ float tile[32][33];
    const int z = blockIdx.z;
    const int type = z / 7, head = z % 7;
    const float* src = (type == 0 ? Wq : (type == 1 ? Wk : Wv)) + head * (HIDDEN * HDIM);
    short* dst = Wt + (size_t)z * (HDIM * HIDDEN);
    const int r0 = blockIdx.x * 32, c0 = blockIdx.y * 32;
    const int tx = threadIdx.x & 31, ty = threadIdx.x >> 5;  // 32 x 8
    for (int i = 0; i < 4; i++)
        tile[ty * 4 + i][tx] = src[(r0 + ty * 4 + i) * HDIM + c0 + tx];
    __syncthreads();
    for (int i = 0; i < 4; i++)
        dst[(c0 + ty * 4 + i) * HIDDEN + r0 + tx] = f2bf(tile[tx][ty * 4 + i]);
}

// ---------------- kernel 2: QKV projection GEMM (128x128 tile) ----------------
// Also scatters line-columns of K and V into compacted Kc / Vct for the far-field
// attention path: pos(t) = 3*(t/7) + rank of (t%7) in sorted {h, h+1, h+3} mod 7.
__global__ __launch_bounds__(256) void qkv_gemm(
    const short* __restrict__ xb, const short* __restrict__ Wt,
    short* __restrict__ Q, short* __restrict__ Kk, short* __restrict__ Vt,
    short* __restrict__ Kc, short* __restrict__ Vct)
{
    __shared__ short Ash[128 * 40];
    __shared__ short Bsh[128 * 40];
    const int m0 = blockIdx.x * 128;
    const int z = blockIdx.y;
    const int head = z % 7, type = z / 7;
    const short* Wz = Wt + (size_t)z * (HDIM * HIDDEN);

    const int tid = threadIdx.x;
    const int wave = tid >> 6, lane = tid & 63;
    const int quad = lane >> 4, l16 = lane & 15;
    const int wm = (wave >> 1) * 64, wn = (wave & 1) * 64;

    f32x4 acc[4][4] = {};
    const int sr = tid >> 2, sc = (tid & 3) * 8;

    for (int k0 = 0; k0 < HIDDEN; k0 += 32) {
        bf16x8 a0 = *(const bf16x8*)(xb + (size_t)(m0 + sr) * HIDDEN + k0 + sc);
        bf16x8 a1 = *(const bf16x8*)(xb + (size_t)(m0 + sr + 64) * HIDDEN + k0 + sc);
        bf16x8 b0 = *(const bf16x8*)(Wz + (size_t)sr * HIDDEN + k0 + sc);
        bf16x8 b1 = *(const bf16x8*)(Wz + (size_t)(sr + 64) * HIDDEN + k0 + sc);
        __syncthreads();
        *(bf16x8*)(Ash + sr * 40 + sc) = a0;
        *(bf16x8*)(Ash + (sr + 64) * 40 + sc) = a1;
        *(bf16x8*)(Bsh + sr * 40 + sc) = b0;
        *(bf16x8*)(Bsh + (sr + 64) * 40 + sc) = b1;
        __syncthreads();
        bf16x8 af[4], bfr[4];
        for (int mi = 0; mi < 4; mi++)
            af[mi] = *(const bf16x8*)(Ash + (wm + mi * 16 + l16) * 40 + quad * 8);
        for (int ni = 0; ni < 4; ni++)
            bfr[ni] = *(const bf16x8*)(Bsh + (wn + ni * 16 + l16) * 40 + quad * 8);
        for (int mi = 0; mi < 4; mi++)
            for (int ni = 0; ni < 4; ni++)
                acc[mi][ni] = __builtin_amdgcn_mfma_f32_16x16x32_bf16(af[mi], bfr[ni], acc[mi][ni], 0, 0, 0);
    }

    // sorted line residues for this head
    int a0r = head, a1r = (head + 1) % 7, a2r = (head + 3) % 7, tswap;
    if (a0r > a1r) { tswap = a0r; a0r = a1r; a1r = tswap; }
    if (a1r > a2r) { tswap = a1r; a1r = a2r; a2r = tswap; }
    if (a0r > a1r) { tswap = a0r; a0r = a1r; a1r = tswap; }

    const size_t base = (size_t)head * (MTOT * HDIM);
    if (type == 0) {
        // fold softmax scale AND log2(e) into Q (softmax done in exp2 domain)
        const float qs = 0.08838834764831845f * 1.4426950408889634f;
        for (int mi = 0; mi < 4; mi++)
            for (int ni = 0; ni < 4; ni++)
                for (int r = 0; r < 4; r++) {
                    int m = m0 + wm + mi * 16 + quad * 4 + r;
                    int n = wn + ni * 16 + l16;
                    Q[base + (size_t)m * HDIM + n] = f2bf(acc[mi][ni][r] * qs);
                }
    } else if (type == 1) {
        for (int mi = 0; mi < 4; mi++)
            for (int ni = 0; ni < 4; ni++)
                for (int r = 0; r < 4; r++) {
                    int m = m0 + wm + mi * 16 + quad * 4 + r;
                    int n = wn + ni * 16 + l16;
                    short v = f2bf(acc[mi][ni][r]);
                    Kk[base + (size_t)m * HDIM + n] = v;
                    int t = m & 2047, bb = m >> 11;
                    int d7 = (t - head + 7) % 7;
                    if ((0x0B >> d7) & 1) {
                        int tres = t % 7;
                        int rank = (tres == a0r) ? 0 : (tres == a1r ? 1 : 2);
                        int pos = 3 * (t / 7) + rank;
                        Kc[(size_t)((head * BB + bb) * CPAD + pos) * HDIM + n] = v;
                    }
                }
    } else {
        for (int mi = 0; mi < 4; mi++)
            for (int ni = 0; ni < 4; ni++) {
                int m = m0 + wm + mi * 16 + quad * 4;
                int bb = m >> 11, t0 = m & 2047;
                int n = wn + ni * 16 + l16;
                short4 o;
                o.x = f2bf(acc[mi][ni][0]); o.y = f2bf(acc[mi][ni][1]);
                o.z = f2bf(acc[mi][ni][2]); o.w = f2bf(acc[mi][ni][3]);
                *(short4*)(Vt + base + (size_t)bb * (HDIM * TT) + (size_t)n * TT + t0) = o;
                short vv[4] = {o.x, o.y, o.z, o.w};
                for (int r = 0; r < 4; r++) {
                    int t = t0 + r;
                    int d7 = (t - head + 7) % 7;
                    if ((0x0B >> d7) & 1) {
                        int tres = t % 7;
                        int rank = (tres == a0r) ? 0 : (tres == a1r ? 1 : 2);
                        int pos = 3 * (t / 7) + rank;
                        Vct[(size_t)((head * BB + bb) * HDIM + n) * CPAD + pos] = vv[r];
                    }
                }
            }
    }
}

// ---------------- kernel 3: fano flash attention v5 (compacted far field) ----------------
// 128-row q-tile per block; far tiles run on line-compacted Kc/Vct (mask-free),
// 3 near tiles use raw K/Vt with the full mask. Row-sums via ones-column MFMA.
// grid: (T/128=16, B=4, HEADS=7), block 256. LDS 45 KB -> 3 blocks/CU.
__global__ __launch_bounds__(256, 3) void fano_attn(
    const short* __restrict__ Q, const short* __restrict__ K, const short* __restrict__ Vt,
    const short* __restrict__ Kc, const short* __restrict__ Vct,
    short* __restrict__ Ocat, const int* __restrict__ iscp)
{
    __shared__ short Ks[64 * 136];
    __shared__ short Vs[128 * 72];
    __shared__ short Ps[4][16 * 72];

    const int causal = *iscp;
    const int qt = (int)gridDim.x - 1 - blockIdx.x;   // longest blocks first (causal)
    const int q0 = qt * 128;
    const int b = blockIdx.y, h = blockIdx.z;
    const int tid = threadIdx.x, wave = tid >> 6, lane = tid & 63;
    const int quad = lane >> 4, l16 = lane & 15;

    const short* Qb = Q + (size_t)(h * MTOT + b * TT + q0) * HDIM;
    const short* Kb = K + (size_t)(h * MTOT + b * TT) * HDIM;
    const short* Vb = Vt + (size_t)h * MTOT * HDIM + (size_t)b * HDIM * TT;
    const short* Kcb = Kc + (size_t)((h * BB + b) * CPAD) * HDIM;
    const short* Vcb = Vct + (size_t)((h * BB + b) * HDIM) * CPAD;

    // sorted line residues; far-field compacted count cfar = #{line cols j < q0-64}
    int a0r = h, a1r = (h + 1) % 7, a2r = (h + 3) % 7, tswap;
    if (a0r > a1r) { tswap = a0r; a0r = a1r; a1r = tswap; }
    if (a1r > a2r) { tswap = a1r; a1r = a2r; a2r = tswap; }
    if (a0r > a1r) { tswap = a0r; a0r = a1r; a1r = tswap; }
    const int X = q0 - 64;
    int cfar = 0;
    if (causal && X > 0) {
        cfar = (X > a0r ? (X - a0r + 6) / 7 : 0)
             + (X > a1r ? (X - a1r + 6) / 7 : 0)
             + (X > a2r ? (X - a2r + 6) / 7 : 0);
    }
    const int nfull = cfar >> 6;
    const int nfar = (cfar + 63) >> 6;
    const int ns = causal ? (q0 >= 64 ? q0 - 64 : 0) : 0;
    const int nn = causal ? (q0 ? 3 : 2) : (TT / 64);
    const int niter = nfar + nn;

    // Q fragments direct from global (scale*log2e folded at projection)
    bf16x8 qf[2][4];
    for (int g = 0; g < 2; g++)
        for (int ks = 0; ks < 4; ks++)
            qf[g][ks] = *(const bf16x8*)(Qb + (size_t)(wave * 32 + g * 16 + l16) * HDIM + ks * 32 + quad * 8);

    float mrun[2][4];
    f32x4 oacc[2][8] = {};
    f32x4 lacc[2] = {};
    int irow[2][4];
    for (int g = 0; g < 2; g++)
        for (int r = 0; r < 4; r++) {
            mrun[g][r] = -1e30f;
            irow[g][r] = q0 + wave * 32 + g * 16 + quad * 4 + r;
        }

    const bf16x8 vones = {0x3F80, 0x3F80, 0x3F80, 0x3F80, 0x3F80, 0x3F80, 0x3F80, 0x3F80};

    int krow[4], kcol[4], vrow[4], vcol[4];
    for (int i = 0; i < 4; i++) {
        int c = tid + i * 256;
        krow[i] = c >> 4; kcol[i] = (c & 15) * 8;
        vrow[i] = c >> 3; vcol[i] = (c & 7) * 8;
    }

    auto tptr = [&](int it, const short*& kp, const short*& vp, int& vstr) {
        if (it < nfar) {
            int c0 = it << 6;
            kp = Kcb + (size_t)c0 * HDIM; vp = Vcb + c0; vstr = CPAD;
        } else {
            int s0 = ns + ((it - nfar) << 6);
            kp = Kb + (size_t)s0 * HDIM; vp = Vb + s0; vstr = TT;
        }
    };

    const short* kp; const short* vp; int vstr;
    tptr(0, kp, vp, vstr);
    bf16x8 kreg[4], vreg[4];
    for (int i = 0; i < 4; i++) {
        kreg[i] = *(const bf16x8*)(kp + (size_t)krow[i] * HDIM + kcol[i]);
        vreg[i] = *(const bf16x8*)(vp + (size_t)vrow[i] * vstr + vcol[i]);
    }

    short* Pw = &Ps[wave][0];

    for (int it = 0; it < niter; it++) {
        __syncthreads();
        for (int i = 0; i < 4; i++) {
            *(bf16x8*)(Ks + krow[i] * 136 + kcol[i]) = kreg[i];
            *(bf16x8*)(Vs + vrow[i] * 72 + vcol[i]) = vreg[i];
        }
        __syncthreads();

        int itn = (it + 1 < niter) ? it + 1 : it;
        tptr(itn, kp, vp, vstr);
        for (int i = 0; i < 4; i++) {
            kreg[i] = *(const bf16x8*)(kp + (size_t)krow[i] * HDIM + kcol[i]);
            vreg[i] = *(const bf16x8*)(vp + (size_t)vrow[i] * vstr + vcol[i]);
        }

        // S = Q K^T (log2 domain)
        f32x4 sacc[2][4] = {};
        for (int ni = 0; ni < 4; ni++)
            for (int ks = 0; ks < 4; ks++) {
                bf16x8 bk = *(const bf16x8*)(Ks + (ni * 16 + l16) * 136 + ks * 32 + quad * 8);
                sacc[0][ni] = __builtin_amdgcn_mfma_f32_16x16x32_bf16(qf[0][ks], bk, sacc[0][ni], 0, 0, 0);
                sacc[1][ni] = __builtin_amdgcn_mfma_f32_16x16x32_bf16(qf[1][ks], bk, sacc[1][ni], 0, 0, 0);
            }

        // mask + row max
        float mx[2][4];
        for (int g = 0; g < 2; g++)
            for (int r = 0; r < 4; r++) mx[g][r] = -1e30f;
        if (it < nfull) {
            // full far tile: mask-free
            for (int ni = 0; ni < 4; ni++)
                for (int g = 0; g < 2; g++)
                    for (int r = 0; r < 4; r++)
                        mx[g][r] = fmaxf(mx[g][r], sacc[g][ni][r]);
        } else if (it < nfar) {
            // partial far tile: tail lanes invalid
            for (int ni = 0; ni < 4; ni++) {
                int c = (it << 6) + ni * 16 + l16;
                bool ok = c < cfar;
                for (int g = 0; g < 2; g++)
                    for (int r = 0; r < 4; r++) {
                        float v = ok ? sacc[g][ni][r] : -1e30f;
                        sacc[g][ni][r] = v;
                        mx[g][r] = fmaxf(mx[g][r], v);
                    }
            }
        } else {
            // near tile: full mask on raw columns
            int s0 = ns + ((it - nfar) << 6);
            for (int ni = 0; ni < 4; ni++) {
                int s = s0 + ni * 16 + l16;
                int d7 = (s - h + 7) % 7;
                bool line = (0x0B >> d7) & 1;
                for (int g = 0; g < 2; g++)
                    for (int r = 0; r < 4; r++) {
                        int i = irow[g][r];
                        bool ok = causal ? ((s <= i) & (line | (s >= i - 16)))
                                         : (line | ((s >= i - 16) & (s <= i + 16)));
                        float v = ok ? sacc[g][ni][r] : -1e30f;
                        sacc[g][ni][r] = v;
                        mx[g][r] = fmaxf(mx[g][r], v);
                    }
            }
        }

        for (int off = 1; off < 16; off <<= 1)
            for (int g = 0; g < 2; g++)
                for (int r = 0; r < 4; r++)
                    mx[g][r] = fmaxf(mx[g][r], __shfl_xor(mx[g][r], off));

        float alpha[2][4];
        for (int g = 0; g < 2; g++)
            for (int r = 0; r < 4; r++) {
                float nm = fmaxf(mrun[g][r], mx[g][r]);
                alpha[g][r] = exp2f(mrun[g][r] - nm);
                mrun[g][r] = nm;
            }
        for (int ni = 0; ni < 4; ni++)
            for (int g = 0; g < 2; g++)
                for (int r = 0; r < 4; r++)
                    sacc[g][ni][r] = exp2f(sacc[g][ni][r] - mrun[g][r]);
        for (int g = 0; g < 2; g++) {
            for (int r = 0; r < 4; r++) lacc[g][r] *= alpha[g][r];
            for (int nj = 0; nj < 8; nj++)
                for (int r = 0; r < 4; r++) oacc[g][nj][r] *= alpha[g][r];
        }

        // per row-group: P -> wave-private LDS -> A-frags; PV + ones-column rowsum
        for (int g = 0; g < 2; g++) {
            for (int ni = 0; ni < 4; ni++)
                for (int r = 0; r < 4; r++)
                    Pw[(quad * 4 + r) * 72 + ni * 16 + l16] = f2bf(sacc[g][ni][r]);
            for (int ks2 = 0; ks2 < 2; ks2++) {
                bf16x8 ap = *(const bf16x8*)(Pw + l16 * 72 + ks2 * 32 + quad * 8);
                lacc[g] = __builtin_amdgcn_mfma_f32_16x16x32_bf16(ap, vones, lacc[g], 0, 0, 0);
                for (int nj = 0; nj < 8; nj++) {
                    bf16x8 bv = *(const bf16x8*)(Vs + (nj * 16 + l16) * 72 + ks2 * 32 + quad * 8);
                    oacc[g][nj] = __builtin_amdgcn_mfma_f32_16x16x32_bf16(ap, bv, oacc[g][nj], 0, 0, 0);
                }
            }
        }
    }

    short* Obase = Ocat + (size_t)(b * TT) * HIDDEN + h * HDIM;
    for (int g = 0; g < 2; g++) {
        float inv[4];
        for (int r = 0; r < 4; r++) inv[r] = 1.0f / lacc[g][r];
        for (int nj = 0; nj < 8; nj++)
            for (int r = 0; r < 4; r++)
                Obase[(size_t)irow[g][r] * HIDDEN + nj * 16 + l16] = f2bf(oacc[g][nj][r] * inv[r]);
    }
}

// ---------------- kernel 4: output projection (128x128 tile) ----------------
__global__ __launch_bounds__(256) void out_gemm(
    const short* __restrict__ A, const short* __restrict__ Bt, float* __restrict__ out)
{
    __shared__ short Ash[128 * 40];
    __shared__ short Bsh[128 * 40];
    const int m0 = blockIdx.x * 128;
    const int n0 = blockIdx.y * 128;

    const int tid = threadIdx.x;
    const int wave = tid >> 6, lane = tid & 63;
    const int quad = lane >> 4, l16 = lane & 15;
    const int wm = (wave >> 1) * 64, wn = (wave & 1) * 64;

    f32x4 acc[4][4] = {};
    const int sr = tid >> 2, sc = (tid & 3) * 8;

    for (int k0 = 0; k0 < HIDDEN; k0 += 32) {
        bf16x8 a0 = *(const bf16x8*)(A + (size_t)(m0 + sr) * HIDDEN + k0 + sc);
        bf16x8 a1 = *(const bf16x8*)(A + (size_t)(m0 + sr + 64) * HIDDEN + k0 + sc);
        bf16x8 b0 = *(const bf16x8*)(Bt + (size_t)(n0 + sr) * HIDDEN + k0 + sc);
        bf16x8 b1 = *(const bf16x8*)(Bt + (size_t)(n0 + sr + 64) * HIDDEN + k0 + sc);
        __syncthreads();
        *(bf16x8*)(Ash + sr * 40 + sc) = a0;
        *(bf16x8*)(Ash + (sr + 64) * 40 + sc) = a1;
        *(bf16x8*)(Bsh + sr * 40 + sc) = b0;
        *(bf16x8*)(Bsh + (sr + 64) * 40 + sc) = b1;
        __syncthreads();
        bf16x8 af[4], bfr[4];
        for (int mi = 0; mi < 4; mi++)
            af[mi] = *(const bf16x8*)(Ash + (wm + mi * 16 + l16) * 40 + quad * 8);
        for (int ni = 0; ni < 4; ni++)
            bfr[ni] = *(const bf16x8*)(Bsh + (wn + ni * 16 + l16) * 40 + quad * 8);
        for (int mi = 0; mi < 4; mi++)
            for (int ni = 0; ni < 4; ni++)
                acc[mi][ni] = __builtin_amdgcn_mfma_f32_16x16x32_bf16(af[mi], bfr[ni], acc[mi][ni], 0, 0, 0);
    }

    for (int mi = 0; mi < 4; mi++)
        for (int ni = 0; ni < 4; ni++)
            for (int r = 0; r < 4; r++) {
                int m = m0 + wm + mi * 16 + quad * 4 + r;
                int n = n0 + wn + ni * 16 + l16;
                out[(size_t)m * HIDDEN + n] = acc[mi][ni][r];
            }
}

extern "C" void kernel_launch(void* const* d_in, const int* in_sizes, int n_in,
                              void* d_out, int out_size, void* d_ws, size_t ws_size,
                              hipStream_t stream) {
    (void)in_sizes; (void)n_in; (void)out_size; (void)ws_size;
    const float* x  = (const float*)d_in[0];
    const float* Wq = (const float*)d_in[1];
    const float* Wk = (const float*)d_in[2];
    const float* Wv = (const float*)d_in[3];
    const float* Wo = (const float*)d_in[4];
    const int* iscp = (const int*)d_in[5];
    float* out = (float*)d_out;

    short* xb   = (short*)d_ws;                       // 8192*896
    short* Qb   = xb   + (size_t)MTOT * HIDDEN;       // 7*8192*128 each
    short* Kb   = Qb   + (size_t)HEADS * MTOT * HDIM;
    short* Vtb  = Kb   + (size_t)HEADS * MTOT * HDIM;
    short* Ocat = Vtb  + (size_t)HEADS * MTOT * HDIM; // 8192*896 (aliased with Wt)
    short* Wt   = Ocat;                               // 21*128*896, used only before attn
    short* Wob  = Ocat + (size_t)MTOT * HIDDEN;       // 896*896
    short* Kcb  = Wob  + (size_t)HIDDEN * HIDDEN;     // 7*4*896*128
    short* Vctb = Kcb  + (size_t)HEADS * BB * CPAD * HDIM;  // 7*4*128*896

    cast_x_kernel<<<(MTOT * HIDDEN) / (256 * 4), 256, 0, stream>>>(x, xb);
    cast_wo_kernel<<<(HIDDEN * HIDDEN) / (256 * 4), 256, 0, stream>>>(Wo, Wob);
    transpose_cast_w<<<dim3(HIDDEN / 32, HDIM / 32, 21), 256, 0, stream>>>(Wq, Wk, Wv, Wt);
    qkv_gemm<<<dim3(MTOT / 128, 21), 256, 0, stream>>>(xb, Wt, Qb, Kb, Vtb, Kcb, Vctb);
    fano_attn<<<dim3(TT / 128, BB, HEADS), 256, 0, stream>>>(Qb, Kb, Vtb, Kcb, Vctb, Ocat, iscp);
    out_gemm<<<dim3(MTOT / 128, HIDDEN / 128), 256, 0, stream>>>(Ocat, Wob, out);
}